// Round 1
// baseline (532.403 us; speedup 1.0000x reference)
//
#include <hip/hip_runtime.h>

#define CHN 512
#define CKD 64
#define NPOS 4096
#define MPOS 1024
#define KC 32

// workspace offsets (floats)
static constexpr size_t OFF_THETA = 0;          // 16*64*4096
static constexpr size_t OFF_O     = 4194304;    // 16*64*4096
static constexpr size_t OFF_PHI   = 8388608;    // 16*64*1024
static constexpr size_t OFF_G     = 9437184;    // 16*64*1024
static constexpr size_t OFF_WTT   = 10485760;   // 512*64
static constexpr size_t OFF_WPT   = 10518528;
static constexpr size_t OFF_WGT   = 10551296;
static constexpr size_t OFF_WOT   = 10584064;   // 64*512

// ---------------------------------------------------------------------------
// K0: transpose weights into k-major layouts for coalesced LDS staging.
//   WtT/WpT/WgT: [512 c][64 o]   WoT: [64 k][512 o]
// ---------------------------------------------------------------------------
__global__ __launch_bounds__(256) void transpose_w_kernel(
    const float* __restrict__ Wt, const float* __restrict__ Wp,
    const float* __restrict__ Wg, const float* __restrict__ Wo,
    float* __restrict__ ws)
{
  int idx = blockIdx.x * 256 + threadIdx.x;   // 0..32767
  int which = blockIdx.y;
  if (which < 3) {
    const float* W = (which == 0) ? Wt : (which == 1) ? Wp : Wg;
    float* outp = ws + ((which == 0) ? OFF_WTT : (which == 1) ? OFF_WPT : OFF_WGT);
    int c = idx >> 6, o = idx & 63;
    outp[idx] = W[o * CHN + c];
  } else {
    float* outp = ws + OFF_WOT;
    int k = idx >> 9, o = idx & 511;
    outp[idx] = Wo[o * CKD + k];
  }
}

// ---------------------------------------------------------------------------
// K1: fused theta/phi/g conv + 2x2 maxpool.
// grid (32 h-pairs, 16 batch), 256 threads. Tile = 2 image rows (128 cols).
// ---------------------------------------------------------------------------
__global__ __launch_bounds__(256) void qkv_kernel(
    const float* __restrict__ x,
    const float* __restrict__ wtT, const float* __restrict__ wpT,
    const float* __restrict__ wgT,
    float* __restrict__ theta, float* __restrict__ phi, float* __restrict__ g)
{
  __shared__ float smem[10240];       // sW[3][KC][64] (6144) + sX[KC][128] (4096)
  float* sW = smem;
  float* sX = smem + 6144;

  const int hp = blockIdx.x;
  const int b  = blockIdx.y;
  const int t  = threadIdx.x;
  const int tr = t >> 4;              // ck base = tr*4
  const int tc = t & 15;              // n  base = tc*8
  const int n0 = hp * 128;

  const float* xb = x + (size_t)b * CHN * NPOS + n0;

  float acc[3][4][8];
#pragma unroll
  for (int m = 0; m < 3; ++m)
#pragma unroll
    for (int i = 0; i < 4; ++i)
#pragma unroll
      for (int j = 0; j < 8; ++j) acc[m][i][j] = 0.f;

  for (int c0 = 0; c0 < CHN; c0 += KC) {
    // stage x chunk [KC][128]
#pragma unroll
    for (int i = 0; i < 4; ++i) {
      int idx = i * 256 + t;          // float4 index 0..1023
      int row = idx >> 5, col4 = idx & 31;
      *(float4*)&sX[row * 128 + col4 * 4] =
          *(const float4*)(xb + (size_t)(c0 + row) * NPOS + col4 * 4);
    }
    // stage weight chunks [KC][64] x3 (k-major)
    const float* wsrc0 = wtT; const float* wsrc1 = wpT; const float* wsrc2 = wgT;
#pragma unroll
    for (int m = 0; m < 3; ++m) {
      const float* wsrc = (m == 0) ? wsrc0 : (m == 1) ? wsrc1 : wsrc2;
#pragma unroll
      for (int i = 0; i < 2; ++i) {
        int idx = i * 256 + t;        // float4 index 0..511
        int row = idx >> 4, col4 = idx & 15;
        *(float4*)&sW[m * 2048 + row * 64 + col4 * 4] =
            *(const float4*)(wsrc + (size_t)(c0 + row) * 64 + col4 * 4);
      }
    }
    __syncthreads();
#pragma unroll 4
    for (int kk = 0; kk < KC; ++kk) {
      float4 b0 = *(const float4*)&sX[kk * 128 + tc * 8];
      float4 b1 = *(const float4*)&sX[kk * 128 + tc * 8 + 4];
      float bx[8] = {b0.x, b0.y, b0.z, b0.w, b1.x, b1.y, b1.z, b1.w};
#pragma unroll
      for (int m = 0; m < 3; ++m) {
        float4 av = *(const float4*)&sW[m * 2048 + kk * 64 + tr * 4];
        float aa[4] = {av.x, av.y, av.z, av.w};
#pragma unroll
        for (int i = 0; i < 4; ++i)
#pragma unroll
          for (int j = 0; j < 8; ++j)
            acc[m][i][j] = fmaf(aa[i], bx[j], acc[m][i][j]);
      }
    }
    __syncthreads();
  }

  // theta: full resolution write
  float* th = theta + (size_t)b * CKD * NPOS + n0;
#pragma unroll
  for (int i = 0; i < 4; ++i) {
    float4 v0 = make_float4(acc[0][i][0], acc[0][i][1], acc[0][i][2], acc[0][i][3]);
    float4 v1 = make_float4(acc[0][i][4], acc[0][i][5], acc[0][i][6], acc[0][i][7]);
    *(float4*)(th + (size_t)(tr * 4 + i) * NPOS + tc * 8) = v0;
    *(float4*)(th + (size_t)(tr * 4 + i) * NPOS + tc * 8 + 4) = v1;
  }

  // phi / g: stage tile in LDS (reuse smem), 2x2 maxpool, write pooled
  float* sPool = smem;                // [64][128]
#pragma unroll
  for (int mm = 1; mm <= 2; ++mm) {
    __syncthreads();                  // previous sPool readers done
#pragma unroll
    for (int i = 0; i < 4; ++i)
#pragma unroll
      for (int j = 0; j < 8; ++j)
        sPool[(tr * 4 + i) * 128 + tc * 8 + j] = acc[mm][i][j];
    __syncthreads();
    float* dst = ((mm == 1) ? phi : g) + (size_t)b * CKD * MPOS + hp * 32;
#pragma unroll
    for (int i = 0; i < 8; ++i) {
      int idx = i * 256 + t;          // 0..2047 = 64ck x 32j
      int ck = idx >> 5, j = idx & 31;
      float v = fmaxf(fmaxf(sPool[ck * 128 + 2 * j], sPool[ck * 128 + 2 * j + 1]),
                      fmaxf(sPool[ck * 128 + 64 + 2 * j], sPool[ck * 128 + 64 + 2 * j + 1]));
      dst[(size_t)ck * MPOS + j] = v;
    }
  }
}

// ---------------------------------------------------------------------------
// K2: fused attention (flash-style, no NxM materialization).
// grid (64 q-tiles, 16 batch), 256 threads = (tx 0..15, ty 0..15).
// Score phase: q = ty*4+i, m = tx*4+j.  O phase: ck = ty+16i, q = tx+16j.
// ---------------------------------------------------------------------------
__global__ __launch_bounds__(256) void attn_kernel(
    const float* __restrict__ theta, const float* __restrict__ phi,
    const float* __restrict__ gmat, float* __restrict__ o)
{
  __shared__ float sTh[64 * 64];      // [ck][q]   uniform-row reads -> no pad
  __shared__ float sPhi[64 * 64];     // [ck][m]   uniform-row reads -> no pad
  __shared__ float sG[64 * 68];       // [ck][m]   padded (row varies per lane)
  __shared__ float sP[64 * 68];       // [q][m]    padded
  __shared__ float sScale[64];
  __shared__ float sL[64];

  const int qt = blockIdx.x;
  const int b  = blockIdx.y;
  const int t  = threadIdx.x;
  const int tx = t & 15;
  const int ty = t >> 4;

  const float* thb = theta + (size_t)b * CKD * NPOS + (size_t)qt * 64;
#pragma unroll
  for (int i = 0; i < 4; ++i) {
    int idx = i * 256 + t;
    int ck = idx >> 4, q4 = idx & 15;
    *(float4*)&sTh[ck * 64 + q4 * 4] = *(const float4*)(thb + (size_t)ck * NPOS + q4 * 4);
  }

  float m_run[4], l_run[4], oacc[4][4];
#pragma unroll
  for (int i = 0; i < 4; ++i) { m_run[i] = -1e30f; l_run[i] = 0.f; }
#pragma unroll
  for (int i = 0; i < 4; ++i)
#pragma unroll
    for (int j = 0; j < 4; ++j) oacc[i][j] = 0.f;

  const float* phb = phi  + (size_t)b * CKD * MPOS;
  const float* gb  = gmat + (size_t)b * CKD * MPOS;

  for (int mt = 0; mt < 16; ++mt) {
#pragma unroll
    for (int i = 0; i < 4; ++i) {
      int idx = i * 256 + t;
      int ck = idx >> 4, m4 = idx & 15;
      *(float4*)&sPhi[ck * 64 + m4 * 4] =
          *(const float4*)(phb + (size_t)ck * MPOS + mt * 64 + m4 * 4);
      *(float4*)&sG[ck * 68 + m4 * 4] =
          *(const float4*)(gb + (size_t)ck * MPOS + mt * 64 + m4 * 4);
    }
    __syncthreads();

    // scores S[q=ty*4+i][m=tx*4+j]
    float s[4][4];
#pragma unroll
    for (int i = 0; i < 4; ++i)
#pragma unroll
      for (int j = 0; j < 4; ++j) s[i][j] = 0.f;
#pragma unroll 4
    for (int ck = 0; ck < 64; ++ck) {
      float4 av = *(const float4*)&sTh[ck * 64 + ty * 4];
      float4 pv = *(const float4*)&sPhi[ck * 64 + tx * 4];
      float aa[4] = {av.x, av.y, av.z, av.w};
      float pp[4] = {pv.x, pv.y, pv.z, pv.w};
#pragma unroll
      for (int i = 0; i < 4; ++i)
#pragma unroll
        for (int j = 0; j < 4; ++j) s[i][j] = fmaf(aa[i], pp[j], s[i][j]);
    }

    // online softmax per q row (replicated across the 16 tx lanes)
#pragma unroll
    for (int i = 0; i < 4; ++i) {
      float rmax = fmaxf(fmaxf(s[i][0], s[i][1]), fmaxf(s[i][2], s[i][3]));
      rmax = fmaxf(rmax, __shfl_xor(rmax, 1, 16));
      rmax = fmaxf(rmax, __shfl_xor(rmax, 2, 16));
      rmax = fmaxf(rmax, __shfl_xor(rmax, 4, 16));
      rmax = fmaxf(rmax, __shfl_xor(rmax, 8, 16));
      float mnew = fmaxf(m_run[i], rmax);
      float sc = __expf(m_run[i] - mnew);
      float rsum = 0.f;
#pragma unroll
      for (int j = 0; j < 4; ++j) {
        float p = __expf(s[i][j] - mnew);
        s[i][j] = p;
        rsum += p;
      }
      rsum += __shfl_xor(rsum, 1, 16);
      rsum += __shfl_xor(rsum, 2, 16);
      rsum += __shfl_xor(rsum, 4, 16);
      rsum += __shfl_xor(rsum, 8, 16);
      l_run[i] = l_run[i] * sc + rsum;
      m_run[i] = mnew;
      if (tx == 0) sScale[ty * 4 + i] = sc;
      *(float4*)&sP[(ty * 4 + i) * 68 + tx * 4] =
          make_float4(s[i][0], s[i][1], s[i][2], s[i][3]);
    }
    __syncthreads();

    // O accumulation: oacc[ck=ty+16i][q=tx+16j]
#pragma unroll
    for (int j = 0; j < 4; ++j) {
      float sc = sScale[tx + 16 * j];
      oacc[0][j] *= sc; oacc[1][j] *= sc; oacc[2][j] *= sc; oacc[3][j] *= sc;
    }
#pragma unroll 4
    for (int m0 = 0; m0 < 64; m0 += 4) {
      float4 gvv[4], pvv[4];
#pragma unroll
      for (int i = 0; i < 4; ++i) gvv[i] = *(const float4*)&sG[(ty + 16 * i) * 68 + m0];
#pragma unroll
      for (int j = 0; j < 4; ++j) pvv[j] = *(const float4*)&sP[(tx + 16 * j) * 68 + m0];
#pragma unroll
      for (int i = 0; i < 4; ++i)
#pragma unroll
        for (int j = 0; j < 4; ++j) {
          oacc[i][j] = fmaf(gvv[i].x, pvv[j].x, oacc[i][j]);
          oacc[i][j] = fmaf(gvv[i].y, pvv[j].y, oacc[i][j]);
          oacc[i][j] = fmaf(gvv[i].z, pvv[j].z, oacc[i][j]);
          oacc[i][j] = fmaf(gvv[i].w, pvv[j].w, oacc[i][j]);
        }
    }
    __syncthreads();                  // protect sPhi/sG/sP reload next iter
  }

  if (tx == 0) {
#pragma unroll
    for (int i = 0; i < 4; ++i) sL[ty * 4 + i] = l_run[i];
  }
  __syncthreads();

  float* ob = o + (size_t)b * CKD * NPOS + (size_t)qt * 64;
#pragma unroll
  for (int i = 0; i < 4; ++i) {
    int ck = ty + 16 * i;
#pragma unroll
    for (int j = 0; j < 4; ++j) {
      int q = tx + 16 * j;
      ob[(size_t)ck * NPOS + q] = oacc[i][j] / sL[q];
    }
  }
}

// ---------------------------------------------------------------------------
// K3: out = x + gamma * (Wo @ o)
// grid (32 n-tiles of 128, 8 co-tiles of 64, 16 batch), 256 threads.
// ---------------------------------------------------------------------------
__global__ __launch_bounds__(256) void outconv_kernel(
    const float* __restrict__ x, const float* __restrict__ woT,
    const float* __restrict__ o, const float* __restrict__ gamma_p,
    float* __restrict__ outp)
{
  __shared__ float sW[64 * 64];       // [k][co]
  __shared__ float sO[64 * 128];      // [k][n]

  const int nt = blockIdx.x;
  const int ct = blockIdx.y;
  const int b  = blockIdx.z;
  const int t  = threadIdx.x;
  const int tr = t >> 4, tc = t & 15;

#pragma unroll
  for (int i = 0; i < 4; ++i) {
    int idx = i * 256 + t;            // 0..1023 float4
    int k = idx >> 4, co4 = idx & 15;
    *(float4*)&sW[k * 64 + co4 * 4] =
        *(const float4*)(woT + (size_t)k * CHN + ct * 64 + co4 * 4);
  }
#pragma unroll
  for (int i = 0; i < 8; ++i) {
    int idx = i * 256 + t;            // 0..2047 float4
    int k = idx >> 5, n4 = idx & 31;
    *(float4*)&sO[k * 128 + n4 * 4] =
        *(const float4*)(o + (size_t)b * CKD * NPOS + (size_t)k * NPOS + nt * 128 + n4 * 4);
  }
  __syncthreads();

  float acc[4][8];
#pragma unroll
  for (int i = 0; i < 4; ++i)
#pragma unroll
    for (int j = 0; j < 8; ++j) acc[i][j] = 0.f;

#pragma unroll 4
  for (int k = 0; k < 64; ++k) {
    float4 av = *(const float4*)&sW[k * 64 + tr * 4];
    float4 b0 = *(const float4*)&sO[k * 128 + tc * 8];
    float4 b1 = *(const float4*)&sO[k * 128 + tc * 8 + 4];
    float aa[4] = {av.x, av.y, av.z, av.w};
    float bx[8] = {b0.x, b0.y, b0.z, b0.w, b1.x, b1.y, b1.z, b1.w};
#pragma unroll
    for (int i = 0; i < 4; ++i)
#pragma unroll
      for (int j = 0; j < 8; ++j)
        acc[i][j] = fmaf(aa[i], bx[j], acc[i][j]);
  }

  float gv = *gamma_p;
  const size_t base = (size_t)b * CHN * NPOS + (size_t)(ct * 64) * NPOS + nt * 128;
#pragma unroll
  for (int i = 0; i < 4; ++i) {
    size_t rowoff = base + (size_t)(tr * 4 + i) * NPOS + tc * 8;
    float4 xv0 = *(const float4*)(x + rowoff);
    float4 xv1 = *(const float4*)(x + rowoff + 4);
    float4 r0, r1;
    r0.x = fmaf(gv, acc[i][0], xv0.x);
    r0.y = fmaf(gv, acc[i][1], xv0.y);
    r0.z = fmaf(gv, acc[i][2], xv0.z);
    r0.w = fmaf(gv, acc[i][3], xv0.w);
    r1.x = fmaf(gv, acc[i][4], xv1.x);
    r1.y = fmaf(gv, acc[i][5], xv1.y);
    r1.z = fmaf(gv, acc[i][6], xv1.z);
    r1.w = fmaf(gv, acc[i][7], xv1.w);
    *(float4*)(outp + rowoff) = r0;
    *(float4*)(outp + rowoff + 4) = r1;
  }
}

// ---------------------------------------------------------------------------
extern "C" void kernel_launch(void* const* d_in, const int* in_sizes, int n_in,
                              void* d_out, int out_size, void* d_ws, size_t ws_size,
                              hipStream_t stream)
{
  const float* x     = (const float*)d_in[0];
  const float* Wt    = (const float*)d_in[1];
  const float* Wp    = (const float*)d_in[2];
  const float* Wg    = (const float*)d_in[3];
  const float* Wo    = (const float*)d_in[4];
  const float* gamma = (const float*)d_in[5];
  float* out = (float*)d_out;
  float* ws  = (float*)d_ws;

  transpose_w_kernel<<<dim3(128, 4), 256, 0, stream>>>(Wt, Wp, Wg, Wo, ws);
  qkv_kernel<<<dim3(32, 16), 256, 0, stream>>>(
      x, ws + OFF_WTT, ws + OFF_WPT, ws + OFF_WGT,
      ws + OFF_THETA, ws + OFF_PHI, ws + OFF_G);
  attn_kernel<<<dim3(64, 16), 256, 0, stream>>>(
      ws + OFF_THETA, ws + OFF_PHI, ws + OFF_G, ws + OFF_O);
  outconv_kernel<<<dim3(32, 8, 16), 256, 0, stream>>>(
      x, ws + OFF_WOT, ws + OFF_O, gamma, out);
}

// Round 2
// 302.273 us; speedup vs baseline: 1.7613x; 1.7613x over previous
//
#include <hip/hip_runtime.h>

#define CHN 512
#define CKD 64
#define NPOS 4096
#define MPOS 1024
#define KC 32

typedef __attribute__((ext_vector_type(8))) short bf16x8;
typedef __attribute__((ext_vector_type(4))) float f32x4;

// workspace offsets (float units)
static constexpr size_t OFF_O   = 0;          // fp32 o [16][64][4096]
static constexpr size_t OFF_THT = 4194304;    // bf16 thetaT [16][4096][64]
static constexpr size_t OFF_PHT = 6291456;    // bf16 phiT   [16][1024][64]
static constexpr size_t OFF_GB  = 6815744;    // bf16 g      [16][64][1024]
static constexpr size_t OFF_WTT = 7340032;    // fp32 WtT [512][64]
static constexpr size_t OFF_WPT = 7372800;
static constexpr size_t OFF_WGT = 7405568;
static constexpr size_t OFF_WOT = 7438336;    // fp32 WoT [64][512]

__device__ inline unsigned short f2bf(float f) {
  union { float f; unsigned int u; } v; v.f = f;
  unsigned int r = v.u + 0x7FFFu + ((v.u >> 16) & 1u);
  return (unsigned short)(r >> 16);
}

// ---------------------------------------------------------------------------
// K0: transpose weights into k-major layouts for coalesced LDS staging.
// ---------------------------------------------------------------------------
__global__ __launch_bounds__(256) void transpose_w_kernel(
    const float* __restrict__ Wt, const float* __restrict__ Wp,
    const float* __restrict__ Wg, const float* __restrict__ Wo,
    float* __restrict__ ws)
{
  int idx = blockIdx.x * 256 + threadIdx.x;   // 0..32767
  int which = blockIdx.y;
  if (which < 3) {
    const float* W = (which == 0) ? Wt : (which == 1) ? Wp : Wg;
    float* outp = ws + ((which == 0) ? OFF_WTT : (which == 1) ? OFF_WPT : OFF_WGT);
    int c = idx >> 6, o = idx & 63;
    outp[idx] = W[o * CHN + c];
  } else {
    float* outp = ws + OFF_WOT;
    int k = idx >> 9, o = idx & 511;
    outp[idx] = Wo[o * CKD + k];
  }
}

// ---------------------------------------------------------------------------
// K1: fused theta/phi/g conv + 2x2 maxpool. fp32 math, bf16 outputs.
//   thetaT [b][n][ck]  phiT [b][m][ck]  g [b][ck][m]
// grid (32 h-pairs, 16 batch), 256 threads. Tile = 2 image rows (128 cols).
// ---------------------------------------------------------------------------
__global__ __launch_bounds__(256) void qkv_kernel(
    const float* __restrict__ x,
    const float* __restrict__ wtT, const float* __restrict__ wpT,
    const float* __restrict__ wgT,
    unsigned short* __restrict__ thT, unsigned short* __restrict__ phT,
    unsigned short* __restrict__ gbf)
{
  __shared__ float smem[10240];       // sW[3][KC][64] (6144) + sX[KC][128] (4096)
  float* sW = smem;
  float* sX = smem + 6144;

  const int hp = blockIdx.x;
  const int b  = blockIdx.y;
  const int t  = threadIdx.x;
  const int tr = t >> 4;              // ck base = tr*4
  const int tc = t & 15;              // n  base = tc*8
  const int n0 = hp * 128;

  const float* xb = x + (size_t)b * CHN * NPOS + n0;

  float acc[3][4][8];
#pragma unroll
  for (int m = 0; m < 3; ++m)
#pragma unroll
    for (int i = 0; i < 4; ++i)
#pragma unroll
      for (int j = 0; j < 8; ++j) acc[m][i][j] = 0.f;

  for (int c0 = 0; c0 < CHN; c0 += KC) {
#pragma unroll
    for (int i = 0; i < 4; ++i) {
      int idx = i * 256 + t;
      int row = idx >> 5, col4 = idx & 31;
      *(float4*)&sX[row * 128 + col4 * 4] =
          *(const float4*)(xb + (size_t)(c0 + row) * NPOS + col4 * 4);
    }
#pragma unroll
    for (int m = 0; m < 3; ++m) {
      const float* wsrc = (m == 0) ? wtT : (m == 1) ? wpT : wgT;
#pragma unroll
      for (int i = 0; i < 2; ++i) {
        int idx = i * 256 + t;
        int row = idx >> 4, col4 = idx & 15;
        *(float4*)&sW[m * 2048 + row * 64 + col4 * 4] =
            *(const float4*)(wsrc + (size_t)(c0 + row) * 64 + col4 * 4);
      }
    }
    __syncthreads();
#pragma unroll 4
    for (int kk = 0; kk < KC; ++kk) {
      float4 b0 = *(const float4*)&sX[kk * 128 + tc * 8];
      float4 b1 = *(const float4*)&sX[kk * 128 + tc * 8 + 4];
      float bx[8] = {b0.x, b0.y, b0.z, b0.w, b1.x, b1.y, b1.z, b1.w};
#pragma unroll
      for (int m = 0; m < 3; ++m) {
        float4 av = *(const float4*)&sW[m * 2048 + kk * 64 + tr * 4];
        float aa[4] = {av.x, av.y, av.z, av.w};
#pragma unroll
        for (int i = 0; i < 4; ++i)
#pragma unroll
          for (int j = 0; j < 8; ++j)
            acc[m][i][j] = fmaf(aa[i], bx[j], acc[m][i][j]);
      }
    }
    __syncthreads();
  }

  // thetaT bf16 [n][ck]
  {
    unsigned short* th = thT + ((size_t)b * NPOS + n0) * 64 + tr * 4;
#pragma unroll
    for (int j = 0; j < 8; ++j) {
      ushort4 v;
      v.x = f2bf(acc[0][0][j]); v.y = f2bf(acc[0][1][j]);
      v.z = f2bf(acc[0][2][j]); v.w = f2bf(acc[0][3][j]);
      *(ushort4*)(th + (size_t)(tc * 8 + j) * 64) = v;
    }
  }

  // phi / g: stage tile in LDS, 2x2 maxpool, write pooled bf16
  float* sPool = smem;                // [64][128]
  unsigned short* phb = phT + (size_t)b * MPOS * 64;       // [m][ck]
  unsigned short* gb  = gbf + (size_t)b * CKD * MPOS;      // [ck][m]
#pragma unroll
  for (int mm = 1; mm <= 2; ++mm) {
    __syncthreads();
#pragma unroll
    for (int i = 0; i < 4; ++i)
#pragma unroll
      for (int j = 0; j < 8; ++j)
        sPool[(tr * 4 + i) * 128 + tc * 8 + j] = acc[mm][i][j];
    __syncthreads();
#pragma unroll
    for (int i = 0; i < 8; ++i) {
      int idx = i * 256 + t;          // 0..2047 = 64ck x 32j
      int ck = idx >> 5, j = idx & 31;
      float v = fmaxf(fmaxf(sPool[ck * 128 + 2 * j], sPool[ck * 128 + 2 * j + 1]),
                      fmaxf(sPool[ck * 128 + 64 + 2 * j], sPool[ck * 128 + 64 + 2 * j + 1]));
      if (mm == 1) phb[(size_t)(hp * 32 + j) * 64 + ck] = f2bf(v);
      else         gb[(size_t)ck * MPOS + hp * 32 + j]  = f2bf(v);
    }
  }
}

// ---------------------------------------------------------------------------
// K2: fused flash attention, bf16 MFMA (16x16x32), fp32 accum.
// grid (64 q-tiles, 16 batch), 256 threads = 4 waves, 16 q-rows/wave.
// LDS tiles XOR-swizzled ((row&7)*8 ushorts) -> all frag reads <=2-way.
// ---------------------------------------------------------------------------
__global__ __launch_bounds__(256) void attn_kernel(
    const unsigned short* __restrict__ thT,  // [b][4096][64]
    const unsigned short* __restrict__ phT,  // [b][1024][64]
    const unsigned short* __restrict__ gbf,  // [b][64][1024]
    float* __restrict__ o)                   // [b][64][4096]
{
  __shared__ unsigned short sTh[64 * 64];   // [q][ck] swizzled
  __shared__ unsigned short sPhi[64 * 64];  // [m][ck] swizzled
  __shared__ unsigned short sG[64 * 64];    // [ck][m] swizzled
  __shared__ unsigned short sP[64 * 64];    // [q][m]  swizzled

  const int qt = blockIdx.x;
  const int b  = blockIdx.y;
  const int t  = threadIdx.x;
  const int w   = t >> 6;
  const int l   = t & 63;
  const int l16 = l & 15;
  const int lhi = l >> 4;

  // stage thetaT tile (64 q rows x 64 ck)
  {
    const unsigned short* src = thT + ((size_t)b * NPOS + (size_t)qt * 64) * 64;
#pragma unroll
    for (int c = t; c < 512; c += 256) {
      int row = c >> 3, c8 = c & 7;
      *(f32x4*)&sTh[row * 64 + ((c8 * 8) ^ ((row & 7) * 8))] =
          *(const f32x4*)(src + row * 64 + c8 * 8);
    }
  }

  f32x4 oacc[4];
  float m_run[4], l_run[4];
#pragma unroll
  for (int i = 0; i < 4; ++i) {
    oacc[i] = (f32x4){0.f, 0.f, 0.f, 0.f};
    m_run[i] = -1e30f; l_run[i] = 0.f;
  }

  const unsigned short* phb = phT + (size_t)b * MPOS * 64;
  const unsigned short* gb  = gbf + (size_t)b * CKD * MPOS;

  for (int mt = 0; mt < 16; ++mt) {
    __syncthreads();                      // prev-iter readers done
#pragma unroll
    for (int c = t; c < 512; c += 256) {  // phiT tile [m][ck]
      int row = c >> 3, c8 = c & 7;
      *(f32x4*)&sPhi[row * 64 + ((c8 * 8) ^ ((row & 7) * 8))] =
          *(const f32x4*)(phb + (size_t)(mt * 64 + row) * 64 + c8 * 8);
    }
#pragma unroll
    for (int c = t; c < 512; c += 256) {  // g tile [ck][m]
      int row = c >> 3, c8 = c & 7;
      *(f32x4*)&sG[row * 64 + ((c8 * 8) ^ ((row & 7) * 8))] =
          *(const f32x4*)(gb + (size_t)row * MPOS + mt * 64 + c8 * 8);
    }
    __syncthreads();

    // scores: S[16q x 64m] per wave, q rows 16w..16w+15
    f32x4 sacc[4];
#pragma unroll
    for (int mf = 0; mf < 4; ++mf) sacc[mf] = (f32x4){0.f, 0.f, 0.f, 0.f};
#pragma unroll
    for (int ks = 0; ks < 2; ++ks) {
      const int q  = 16 * w + l16;
      const int ob = lhi * 8 + 32 * ks;
      bf16x8 a = *(const bf16x8*)&sTh[q * 64 + (ob ^ ((q & 7) * 8))];
#pragma unroll
      for (int mf = 0; mf < 4; ++mf) {
        const int m = l16 + 16 * mf;
        bf16x8 bb = *(const bf16x8*)&sPhi[m * 64 + (ob ^ ((m & 7) * 8))];
        sacc[mf] = __builtin_amdgcn_mfma_f32_16x16x32_bf16(a, bb, sacc[mf], 0, 0, 0);
      }
    }

    // online softmax: lane's rows are q = 16w + lhi*4 + r (same rows as PV D)
    float sc[4];
#pragma unroll
    for (int r = 0; r < 4; ++r) {
      float mx = fmaxf(fmaxf(sacc[0][r], sacc[1][r]), fmaxf(sacc[2][r], sacc[3][r]));
      mx = fmaxf(mx, __shfl_xor(mx, 1, 64));
      mx = fmaxf(mx, __shfl_xor(mx, 2, 64));
      mx = fmaxf(mx, __shfl_xor(mx, 4, 64));
      mx = fmaxf(mx, __shfl_xor(mx, 8, 64));
      float mnew = fmaxf(m_run[r], mx);
      sc[r] = __expf(m_run[r] - mnew);
      m_run[r] = mnew;
      float rs = 0.f;
#pragma unroll
      for (int mf = 0; mf < 4; ++mf) {
        float p = __expf(sacc[mf][r] - mnew);
        sacc[mf][r] = p;
        rs += p;
      }
      rs += __shfl_xor(rs, 1, 64);
      rs += __shfl_xor(rs, 2, 64);
      rs += __shfl_xor(rs, 4, 64);
      rs += __shfl_xor(rs, 8, 64);
      l_run[r] = l_run[r] * sc[r] + rs;
    }

    // write P (bf16) to swizzled sP; same-wave consumption only
#pragma unroll
    for (int r = 0; r < 4; ++r) {
      const int qq = 16 * w + lhi * 4 + r;
      const int swz = (qq & 7) * 8;
#pragma unroll
      for (int mf = 0; mf < 4; ++mf) {
        const int m = l16 + 16 * mf;
        sP[qq * 64 + ((m & 0x38) ^ swz) + (m & 7)] = f2bf(sacc[mf][r]);
      }
    }

    // rescale O accumulators
#pragma unroll
    for (int ckf = 0; ckf < 4; ++ckf)
#pragma unroll
      for (int r = 0; r < 4; ++r) oacc[ckf][r] *= sc[r];

    // PV: O[16q x 64ck] += P[16q x 64m] * gT[64m x 64ck]
#pragma unroll
    for (int ks = 0; ks < 2; ++ks) {
      const int q  = 16 * w + l16;
      const int ob = lhi * 8 + 32 * ks;
      bf16x8 a = *(const bf16x8*)&sP[q * 64 + (ob ^ ((q & 7) * 8))];
#pragma unroll
      for (int ckf = 0; ckf < 4; ++ckf) {
        const int ck = l16 + 16 * ckf;
        bf16x8 bb = *(const bf16x8*)&sG[ck * 64 + (ob ^ ((ck & 7) * 8))];
        oacc[ckf] = __builtin_amdgcn_mfma_f32_16x16x32_bf16(a, bb, oacc[ckf], 0, 0, 0);
      }
    }
  }

  // epilogue: normalize and write o[b][ck][n] (float4 along n)
  float inv[4];
#pragma unroll
  for (int r = 0; r < 4; ++r) inv[r] = 1.0f / l_run[r];
#pragma unroll
  for (int ckf = 0; ckf < 4; ++ckf) {
    const int ck = l16 + 16 * ckf;
    f32x4 v;
#pragma unroll
    for (int r = 0; r < 4; ++r) v[r] = oacc[ckf][r] * inv[r];
    *(f32x4*)(o + ((size_t)b * CKD + ck) * NPOS + qt * 64 + 16 * w + lhi * 4) = v;
  }
}

// ---------------------------------------------------------------------------
// K3: out = x + gamma * (Wo @ o)
// grid (32 n-tiles of 128, 8 co-tiles of 64, 16 batch), 256 threads.
// ---------------------------------------------------------------------------
__global__ __launch_bounds__(256) void outconv_kernel(
    const float* __restrict__ x, const float* __restrict__ woT,
    const float* __restrict__ o, const float* __restrict__ gamma_p,
    float* __restrict__ outp)
{
  __shared__ float sW[64 * 64];       // [k][co]
  __shared__ float sO[64 * 128];      // [k][n]

  const int nt = blockIdx.x;
  const int ct = blockIdx.y;
  const int b  = blockIdx.z;
  const int t  = threadIdx.x;
  const int tr = t >> 4, tc = t & 15;

#pragma unroll
  for (int i = 0; i < 4; ++i) {
    int idx = i * 256 + t;
    int k = idx >> 4, co4 = idx & 15;
    *(float4*)&sW[k * 64 + co4 * 4] =
        *(const float4*)(woT + (size_t)k * CHN + ct * 64 + co4 * 4);
  }
#pragma unroll
  for (int i = 0; i < 8; ++i) {
    int idx = i * 256 + t;
    int k = idx >> 5, n4 = idx & 31;
    *(float4*)&sO[k * 128 + n4 * 4] =
        *(const float4*)(o + (size_t)b * CKD * NPOS + (size_t)k * NPOS + nt * 128 + n4 * 4);
  }
  __syncthreads();

  float acc[4][8];
#pragma unroll
  for (int i = 0; i < 4; ++i)
#pragma unroll
    for (int j = 0; j < 8; ++j) acc[i][j] = 0.f;

#pragma unroll 4
  for (int k = 0; k < 64; ++k) {
    float4 av = *(const float4*)&sW[k * 64 + tr * 4];
    float4 b0 = *(const float4*)&sO[k * 128 + tc * 8];
    float4 b1 = *(const float4*)&sO[k * 128 + tc * 8 + 4];
    float aa[4] = {av.x, av.y, av.z, av.w};
    float bx[8] = {b0.x, b0.y, b0.z, b0.w, b1.x, b1.y, b1.z, b1.w};
#pragma unroll
    for (int i = 0; i < 4; ++i)
#pragma unroll
      for (int j = 0; j < 8; ++j)
        acc[i][j] = fmaf(aa[i], bx[j], acc[i][j]);
  }

  float gv = *gamma_p;
  const size_t base = (size_t)b * CHN * NPOS + (size_t)(ct * 64) * NPOS + nt * 128;
#pragma unroll
  for (int i = 0; i < 4; ++i) {
    size_t rowoff = base + (size_t)(tr * 4 + i) * NPOS + tc * 8;
    float4 xv0 = *(const float4*)(x + rowoff);
    float4 xv1 = *(const float4*)(x + rowoff + 4);
    float4 r0, r1;
    r0.x = fmaf(gv, acc[i][0], xv0.x);
    r0.y = fmaf(gv, acc[i][1], xv0.y);
    r0.z = fmaf(gv, acc[i][2], xv0.z);
    r0.w = fmaf(gv, acc[i][3], xv0.w);
    r1.x = fmaf(gv, acc[i][4], xv1.x);
    r1.y = fmaf(gv, acc[i][5], xv1.y);
    r1.z = fmaf(gv, acc[i][6], xv1.z);
    r1.w = fmaf(gv, acc[i][7], xv1.w);
    *(float4*)(outp + rowoff) = r0;
    *(float4*)(outp + rowoff + 4) = r1;
  }
}

// ---------------------------------------------------------------------------
extern "C" void kernel_launch(void* const* d_in, const int* in_sizes, int n_in,
                              void* d_out, int out_size, void* d_ws, size_t ws_size,
                              hipStream_t stream)
{
  const float* x     = (const float*)d_in[0];
  const float* Wt    = (const float*)d_in[1];
  const float* Wp    = (const float*)d_in[2];
  const float* Wg    = (const float*)d_in[3];
  const float* Wo    = (const float*)d_in[4];
  const float* gamma = (const float*)d_in[5];
  float* out = (float*)d_out;
  float* ws  = (float*)d_ws;

  float* o_f            = ws + OFF_O;
  unsigned short* thT   = (unsigned short*)(ws + OFF_THT);
  unsigned short* phT   = (unsigned short*)(ws + OFF_PHT);
  unsigned short* gbf   = (unsigned short*)(ws + OFF_GB);

  transpose_w_kernel<<<dim3(128, 4), 256, 0, stream>>>(Wt, Wp, Wg, Wo, ws);
  qkv_kernel<<<dim3(32, 16), 256, 0, stream>>>(
      x, ws + OFF_WTT, ws + OFF_WPT, ws + OFF_WGT, thT, phT, gbf);
  attn_kernel<<<dim3(64, 16), 256, 0, stream>>>(thT, phT, gbf, o_f);
  outconv_kernel<<<dim3(32, 8, 16), 256, 0, stream>>>(
      x, ws + OFF_WOT, o_f, gamma, out);
}

// Round 4
// 184.260 us; speedup vs baseline: 2.8894x; 1.6405x over previous
//
#include <hip/hip_runtime.h>

#define CHN 512
#define CKD 64
#define NPOS 4096
#define MPOS 1024

typedef __attribute__((ext_vector_type(8))) short bf16x8;
typedef __attribute__((ext_vector_type(4))) float f32x4;
typedef __attribute__((ext_vector_type(8))) unsigned short u16x8;

// workspace offsets (float units)
static constexpr size_t OFF_O   = 0;          // fp32 o [16][64][4096]
static constexpr size_t OFF_THT = 4194304;    // bf16 thetaT [16][4096][64]
static constexpr size_t OFF_PHT = 6291456;    // bf16 phiT   [16][1024][64]
static constexpr size_t OFF_GB  = 6815744;    // bf16 g      [16][64][1024]
static constexpr size_t OFF_WBF = 7340032;    // bf16 W[3][64][512] (k-minor, natural)
static constexpr size_t OFF_WOT = 7389184;    // fp32 WoT [64][512]

__device__ __forceinline__ unsigned short f2bf(float f) {
  union { float f; unsigned int u; } v; v.f = f;
  unsigned int r = v.u + 0x7FFFu + ((v.u >> 16) & 1u);
  return (unsigned short)(r >> 16);
}

__device__ __forceinline__ void gl2lds16(const void* g, void* l) {
  __builtin_amdgcn_global_load_lds(
      (const __attribute__((address_space(1))) unsigned int*)g,
      (__attribute__((address_space(3))) unsigned int*)l, 16, 0, 0);
}

// ---------------------------------------------------------------------------
// K0: weight prep. Wt/Wp/Wg fp32 [64][512] -> bf16 [3][64][512] (no transpose,
// already k-minor for MFMA B-operand). Wo [512][64] -> WoT fp32 [64][512].
// ---------------------------------------------------------------------------
__global__ __launch_bounds__(256) void prep_w_kernel(
    const float* __restrict__ Wt, const float* __restrict__ Wp,
    const float* __restrict__ Wg, const float* __restrict__ Wo,
    unsigned short* __restrict__ wbf, float* __restrict__ woT)
{
  int id = blockIdx.x * 256 + threadIdx.x;   // 0..131071
  if (id < 98304) {
    int mat = id >> 15, r = id & 32767;
    const float* W = (mat == 0) ? Wt : (mat == 1) ? Wp : Wg;
    wbf[id] = f2bf(W[r]);
  } else {
    int j = id - 98304;                      // 0..32767
    int k = j >> 9, o2 = j & 511;
    woT[j] = Wo[o2 * CKD + k];
  }
}

// ---------------------------------------------------------------------------
// K1a: transpose+convert x [b][512 c][4096 n] fp32 -> xT [b][4096 n][512 c] bf16.
// LDS-tiled 64c x 64n; both global sides coalesced. grid (64 n-tiles, 16 b).
// ---------------------------------------------------------------------------
__global__ __launch_bounds__(256) void transpose_x_kernel(
    const float* __restrict__ x, unsigned short* __restrict__ xT)
{
  __shared__ unsigned short sT[64 * 68];     // pad 4 ushorts
  const int nt = blockIdx.x, b = blockIdx.y, t = threadIdx.x;
  const int n0 = nt * 64;

  for (int c0 = 0; c0 < CHN; c0 += 64) {
    if (c0) __syncthreads();                 // previous subtile readers done
#pragma unroll
    for (int i = 0; i < 4; ++i) {
      int idx = i * 256 + t;                 // 0..1023 float4
      int cc = idx >> 4, f4 = idx & 15;
      float4 v = *(const float4*)(x + ((size_t)b * CHN + c0 + cc) * NPOS + n0 + f4 * 4);
      ushort4 u;
      u.x = f2bf(v.x); u.y = f2bf(v.y); u.z = f2bf(v.z); u.w = f2bf(v.w);
      *(ushort4*)&sT[cc * 68 + f4 * 4] = u;
    }
    __syncthreads();
#pragma unroll
    for (int i = 0; i < 2; ++i) {
      int idx = i * 256 + t;                 // 0..511
      int nn = idx >> 3, co = idx & 7;
      u16x8 u;
#pragma unroll
      for (int e = 0; e < 8; ++e) u[e] = sT[(co * 8 + e) * 68 + nn];
      *(u16x8*)(xT + ((size_t)b * NPOS + n0 + nn) * CHN + c0 + co * 8) = u;  // FIX: + c0
    }
  }
}

// ---------------------------------------------------------------------------
// K1b: qkv GEMM via MFMA. D[n][ck] = xT[n][c] * W[ck][c]^T for 3 matrices.
// grid (32 n-tiles of 128, 16 b), 256 thr = 4 waves.
// Wave w: n-frags at 16w and 64+16w (h / h+1 pairing for in-register maxpool).
// Staging via global_load_lds(16B) with row-XOR-swizzled SOURCE (LDS linear).
// Outputs: thetaT bf16 [n][ck]; phi pooled [m][ck]; g pooled [ck][m].
// ---------------------------------------------------------------------------
__global__ __launch_bounds__(256) void qkv_mfma_kernel(
    const unsigned short* __restrict__ xT,   // [b][4096][512]
    const unsigned short* __restrict__ wbf,  // [3][64][512]
    unsigned short* __restrict__ thT, unsigned short* __restrict__ phT,
    unsigned short* __restrict__ gbf)
{
  __shared__ unsigned short sX[128 * 64];    // [rn][c] rows 128B, swizzled content
  __shared__ unsigned short sW[3 * 64 * 64]; // [mat][ck][c] rows 128B, swizzled

  const int bx = blockIdx.x;
  const int b  = blockIdx.y;
  const int t  = threadIdx.x;
  const int w   = t >> 6;
  const int l   = t & 63;
  const int l16 = l & 15;
  const int lhi = l >> 4;
  const int n0  = bx * 128;

  f32x4 acc[3][2][4];
#pragma unroll
  for (int m = 0; m < 3; ++m)
#pragma unroll
    for (int nf = 0; nf < 2; ++nf)
#pragma unroll
      for (int ckf = 0; ckf < 4; ++ckf) acc[m][nf][ckf] = (f32x4){0.f, 0.f, 0.f, 0.f};

  for (int c0 = 0; c0 < CHN; c0 += 64) {
    if (c0) __syncthreads();                 // protect LDS reuse
    // stage xT tile: 128 rows x 128 B
#pragma unroll
    for (int i = 0; i < 4; ++i) {
      int row = (i * 4 + w) * 8 + (l >> 3);  // 0..127
      int sbyte = (l & 7) * 16;
      const char* g = (const char*)xT +
          ((((size_t)b * NPOS + n0 + row) * CHN + c0) << 1) + (sbyte ^ ((row & 7) << 4));
      gl2lds16(g, (char*)sX + (i * 4 + w) * 1024);
    }
    // stage W tiles: 3 x 64 rows x 128 B
#pragma unroll
    for (int mi = 0; mi < 6; ++mi) {
      int mat = mi >> 1;
      int row = ((mi & 1) * 4 + w) * 8 + (l >> 3);   // 0..63
      int sbyte = (l & 7) * 16;
      const char* g = (const char*)wbf +
          ((((size_t)mat * 64 + row) * CHN + c0) << 1) + (sbyte ^ ((row & 7) << 4));
      gl2lds16(g, (char*)sW + mi * 4096 + w * 1024);
    }
    __syncthreads();

#pragma unroll
    for (int ks = 0; ks < 2; ++ks) {
      const int cu = ks * 32 + lhi * 8;      // ushort col
      bf16x8 a[2];
#pragma unroll
      for (int nf = 0; nf < 2; ++nf) {
        int rn = 16 * w + 64 * nf + l16;
        a[nf] = *(const bf16x8*)&sX[rn * 64 + (cu ^ ((rn & 7) * 8))];
      }
#pragma unroll
      for (int m = 0; m < 3; ++m)
#pragma unroll
        for (int ckf = 0; ckf < 4; ++ckf) {
          int rw = ckf * 16 + l16;
          bf16x8 bb = *(const bf16x8*)&sW[m * 4096 + rw * 64 + (cu ^ ((rw & 7) * 8))];
          acc[m][0][ckf] = __builtin_amdgcn_mfma_f32_16x16x32_bf16(a[0], bb, acc[m][0][ckf], 0, 0, 0);
          acc[m][1][ckf] = __builtin_amdgcn_mfma_f32_16x16x32_bf16(a[1], bb, acc[m][1][ckf], 0, 0, 0);
        }
    }
  }

  // epilogue: theta full-res [n][ck] bf16
  unsigned short* th = thT + (size_t)b * NPOS * 64;
#pragma unroll
  for (int nf = 0; nf < 2; ++nf)
#pragma unroll
    for (int r = 0; r < 4; ++r) {
      int n = n0 + 16 * w + 64 * nf + lhi * 4 + r;
#pragma unroll
      for (int ckf = 0; ckf < 4; ++ckf)
        th[(size_t)n * 64 + ckf * 16 + l16] = f2bf(acc[0][nf][ckf][r]);
    }

  // phi/g: 2x2 maxpool in-register. pooled row = bx, col j = 8w + lhi*2 + pr.
  unsigned short* ph = phT + (size_t)b * MPOS * 64;
  unsigned short* gb = gbf + (size_t)b * CKD * MPOS;
#pragma unroll
  for (int pr = 0; pr < 2; ++pr) {
    int mcol = bx * 32 + 8 * w + lhi * 2 + pr;
#pragma unroll
    for (int ckf = 0; ckf < 4; ++ckf) {
      int ck = ckf * 16 + l16;
      float vp = fmaxf(fmaxf(acc[1][0][ckf][2 * pr], acc[1][0][ckf][2 * pr + 1]),
                       fmaxf(acc[1][1][ckf][2 * pr], acc[1][1][ckf][2 * pr + 1]));
      float vg = fmaxf(fmaxf(acc[2][0][ckf][2 * pr], acc[2][0][ckf][2 * pr + 1]),
                       fmaxf(acc[2][1][ckf][2 * pr], acc[2][1][ckf][2 * pr + 1]));
      ph[(size_t)mcol * 64 + ck] = f2bf(vp);
      gb[(size_t)ck * MPOS + mcol] = f2bf(vg);
    }
  }
}

// ---------------------------------------------------------------------------
// K2: fused flash attention, bf16 MFMA (16x16x32), fp32 accum. (unchanged)
// ---------------------------------------------------------------------------
__global__ __launch_bounds__(256) void attn_kernel(
    const unsigned short* __restrict__ thT,  // [b][4096][64]
    const unsigned short* __restrict__ phT,  // [b][1024][64]
    const unsigned short* __restrict__ gbf,  // [b][64][1024]
    float* __restrict__ o)                   // [b][64][4096]
{
  __shared__ unsigned short sTh[64 * 64];
  __shared__ unsigned short sPhi[64 * 64];
  __shared__ unsigned short sG[64 * 64];
  __shared__ unsigned short sP[64 * 64];

  const int qt = blockIdx.x;
  const int b  = blockIdx.y;
  const int t  = threadIdx.x;
  const int w   = t >> 6;
  const int l   = t & 63;
  const int l16 = l & 15;
  const int lhi = l >> 4;

  {
    const unsigned short* src = thT + ((size_t)b * NPOS + (size_t)qt * 64) * 64;
#pragma unroll
    for (int c = t; c < 512; c += 256) {
      int row = c >> 3, c8 = c & 7;
      *(f32x4*)&sTh[row * 64 + ((c8 * 8) ^ ((row & 7) * 8))] =
          *(const f32x4*)(src + row * 64 + c8 * 8);
    }
  }

  f32x4 oacc[4];
  float m_run[4], l_run[4];
#pragma unroll
  for (int i = 0; i < 4; ++i) {
    oacc[i] = (f32x4){0.f, 0.f, 0.f, 0.f};
    m_run[i] = -1e30f; l_run[i] = 0.f;
  }

  const unsigned short* phb = phT + (size_t)b * MPOS * 64;
  const unsigned short* gb  = gbf + (size_t)b * CKD * MPOS;

  for (int mt = 0; mt < 16; ++mt) {
    __syncthreads();
#pragma unroll
    for (int c = t; c < 512; c += 256) {
      int row = c >> 3, c8 = c & 7;
      *(f32x4*)&sPhi[row * 64 + ((c8 * 8) ^ ((row & 7) * 8))] =
          *(const f32x4*)(phb + (size_t)(mt * 64 + row) * 64 + c8 * 8);
    }
#pragma unroll
    for (int c = t; c < 512; c += 256) {
      int row = c >> 3, c8 = c & 7;
      *(f32x4*)&sG[row * 64 + ((c8 * 8) ^ ((row & 7) * 8))] =
          *(const f32x4*)(gb + (size_t)row * MPOS + mt * 64 + c8 * 8);
    }
    __syncthreads();

    f32x4 sacc[4];
#pragma unroll
    for (int mf = 0; mf < 4; ++mf) sacc[mf] = (f32x4){0.f, 0.f, 0.f, 0.f};
#pragma unroll
    for (int ks = 0; ks < 2; ++ks) {
      const int q  = 16 * w + l16;
      const int ob = lhi * 8 + 32 * ks;
      bf16x8 a = *(const bf16x8*)&sTh[q * 64 + (ob ^ ((q & 7) * 8))];
#pragma unroll
      for (int mf = 0; mf < 4; ++mf) {
        const int m = l16 + 16 * mf;
        bf16x8 bb = *(const bf16x8*)&sPhi[m * 64 + (ob ^ ((m & 7) * 8))];
        sacc[mf] = __builtin_amdgcn_mfma_f32_16x16x32_bf16(a, bb, sacc[mf], 0, 0, 0);
      }
    }

    float sc[4];
#pragma unroll
    for (int r = 0; r < 4; ++r) {
      float mx = fmaxf(fmaxf(sacc[0][r], sacc[1][r]), fmaxf(sacc[2][r], sacc[3][r]));
      mx = fmaxf(mx, __shfl_xor(mx, 1, 64));
      mx = fmaxf(mx, __shfl_xor(mx, 2, 64));
      mx = fmaxf(mx, __shfl_xor(mx, 4, 64));
      mx = fmaxf(mx, __shfl_xor(mx, 8, 64));
      float mnew = fmaxf(m_run[r], mx);
      sc[r] = __expf(m_run[r] - mnew);
      m_run[r] = mnew;
      float rs = 0.f;
#pragma unroll
      for (int mf = 0; mf < 4; ++mf) {
        float p = __expf(sacc[mf][r] - mnew);
        sacc[mf][r] = p;
        rs += p;
      }
      rs += __shfl_xor(rs, 1, 64);
      rs += __shfl_xor(rs, 2, 64);
      rs += __shfl_xor(rs, 4, 64);
      rs += __shfl_xor(rs, 8, 64);
      l_run[r] = l_run[r] * sc[r] + rs;
    }

#pragma unroll
    for (int r = 0; r < 4; ++r) {
      const int qq = 16 * w + lhi * 4 + r;
      const int swz = (qq & 7) * 8;
#pragma unroll
      for (int mf = 0; mf < 4; ++mf) {
        const int m = l16 + 16 * mf;
        sP[qq * 64 + ((m & 0x38) ^ swz) + (m & 7)] = f2bf(sacc[mf][r]);
      }
    }

#pragma unroll
    for (int ckf = 0; ckf < 4; ++ckf)
#pragma unroll
      for (int r = 0; r < 4; ++r) oacc[ckf][r] *= sc[r];

#pragma unroll
    for (int ks = 0; ks < 2; ++ks) {
      const int q  = 16 * w + l16;
      const int ob = lhi * 8 + 32 * ks;
      bf16x8 a = *(const bf16x8*)&sP[q * 64 + (ob ^ ((q & 7) * 8))];
#pragma unroll
      for (int ckf = 0; ckf < 4; ++ckf) {
        const int ck = l16 + 16 * ckf;
        bf16x8 bb = *(const bf16x8*)&sG[ck * 64 + (ob ^ ((ck & 7) * 8))];
        oacc[ckf] = __builtin_amdgcn_mfma_f32_16x16x32_bf16(a, bb, oacc[ckf], 0, 0, 0);
      }
    }
  }

  float inv[4];
#pragma unroll
  for (int r = 0; r < 4; ++r) inv[r] = 1.0f / l_run[r];
#pragma unroll
  for (int ckf = 0; ckf < 4; ++ckf) {
    const int ck = l16 + 16 * ckf;
    f32x4 v;
#pragma unroll
    for (int r = 0; r < 4; ++r) v[r] = oacc[ckf][r] * inv[r];
    *(f32x4*)(o + ((size_t)b * CKD + ck) * NPOS + qt * 64 + 16 * w + lhi * 4) = v;
  }
}

// ---------------------------------------------------------------------------
// K3: out = x + gamma * (Wo @ o)  (unchanged; ~memory-floor already)
// ---------------------------------------------------------------------------
__global__ __launch_bounds__(256) void outconv_kernel(
    const float* __restrict__ x, const float* __restrict__ woT,
    const float* __restrict__ o, const float* __restrict__ gamma_p,
    float* __restrict__ outp)
{
  __shared__ float sW[64 * 64];
  __shared__ float sO[64 * 128];

  const int nt = blockIdx.x;
  const int ct = blockIdx.y;
  const int b  = blockIdx.z;
  const int t  = threadIdx.x;
  const int tr = t >> 4, tc = t & 15;

#pragma unroll
  for (int i = 0; i < 4; ++i) {
    int idx = i * 256 + t;
    int k = idx >> 4, co4 = idx & 15;
    *(float4*)&sW[k * 64 + co4 * 4] =
        *(const float4*)(woT + (size_t)k * CHN + ct * 64 + co4 * 4);
  }
#pragma unroll
  for (int i = 0; i < 8; ++i) {
    int idx = i * 256 + t;
    int k = idx >> 5, n4 = idx & 31;
    *(float4*)&sO[k * 128 + n4 * 4] =
        *(const float4*)(o + (size_t)b * CKD * NPOS + (size_t)k * NPOS + nt * 128 + n4 * 4);
  }
  __syncthreads();

  float acc[4][8];
#pragma unroll
  for (int i = 0; i < 4; ++i)
#pragma unroll
    for (int j = 0; j < 8; ++j) acc[i][j] = 0.f;

#pragma unroll 4
  for (int k = 0; k < 64; ++k) {
    float4 av = *(const float4*)&sW[k * 64 + tr * 4];
    float4 b0 = *(const float4*)&sO[k * 128 + tc * 8];
    float4 b1 = *(const float4*)&sO[k * 128 + tc * 8 + 4];
    float aa[4] = {av.x, av.y, av.z, av.w};
    float bx[8] = {b0.x, b0.y, b0.z, b0.w, b1.x, b1.y, b1.z, b1.w};
#pragma unroll
    for (int i = 0; i < 4; ++i)
#pragma unroll
      for (int j = 0; j < 8; ++j)
        acc[i][j] = fmaf(aa[i], bx[j], acc[i][j]);
  }

  float gv = *gamma_p;
  const size_t base = (size_t)b * CHN * NPOS + (size_t)(ct * 64) * NPOS + nt * 128;
#pragma unroll
  for (int i = 0; i < 4; ++i) {
    size_t rowoff = base + (size_t)(tr * 4 + i) * NPOS + tc * 8;
    float4 xv0 = *(const float4*)(x + rowoff);
    float4 xv1 = *(const float4*)(x + rowoff + 4);
    float4 r0, r1;
    r0.x = fmaf(gv, acc[i][0], xv0.x);
    r0.y = fmaf(gv, acc[i][1], xv0.y);
    r0.z = fmaf(gv, acc[i][2], xv0.z);
    r0.w = fmaf(gv, acc[i][3], xv0.w);
    r1.x = fmaf(gv, acc[i][4], xv1.x);
    r1.y = fmaf(gv, acc[i][5], xv1.y);
    r1.z = fmaf(gv, acc[i][6], xv1.z);
    r1.w = fmaf(gv, acc[i][7], xv1.w);
    *(float4*)(outp + rowoff) = r0;
    *(float4*)(outp + rowoff + 4) = r1;
  }
}

// ---------------------------------------------------------------------------
extern "C" void kernel_launch(void* const* d_in, const int* in_sizes, int n_in,
                              void* d_out, int out_size, void* d_ws, size_t ws_size,
                              hipStream_t stream)
{
  const float* x     = (const float*)d_in[0];
  const float* Wt    = (const float*)d_in[1];
  const float* Wp    = (const float*)d_in[2];
  const float* Wg    = (const float*)d_in[3];
  const float* Wo    = (const float*)d_in[4];
  const float* gamma = (const float*)d_in[5];
  float* out = (float*)d_out;
  float* ws  = (float*)d_ws;

  float* o_f          = ws + OFF_O;
  unsigned short* thT = (unsigned short*)(ws + OFF_THT);
  unsigned short* phT = (unsigned short*)(ws + OFF_PHT);
  unsigned short* gbf = (unsigned short*)(ws + OFF_GB);
  unsigned short* wbf = (unsigned short*)(ws + OFF_WBF);
  float* woT          = ws + OFF_WOT;
  // xT bf16 [16][4096][512] = 67 MB scratch in d_out's 134 MB; fully consumed
  // by qkv_mfma before outconv overwrites d_out. Rewritten every call.
  unsigned short* xT  = (unsigned short*)d_out;

  prep_w_kernel<<<dim3(512), 256, 0, stream>>>(Wt, Wp, Wg, Wo, wbf, woT);
  transpose_x_kernel<<<dim3(64, 16), 256, 0, stream>>>(x, xT);
  qkv_mfma_kernel<<<dim3(32, 16), 256, 0, stream>>>(xT, wbf, thT, phT, gbf);
  attn_kernel<<<dim3(64, 16), 256, 0, stream>>>(thT, phT, gbf, o_f);
  outconv_kernel<<<dim3(32, 8, 16), 256, 0, stream>>>(x, woT, o_f, gamma, out);
}